// Round 1
// baseline (12884.550 us; speedup 1.0000x reference)
//
#include <hip/hip_runtime.h>
#include <hip/hip_bf16.h>
#include <math.h>

#define D_MODEL 4096
#define N_HEADS 128
#define LATENT  512
#define ROPE_D  64
#define HEAD_D  32
#define BATCH   2
#define SEQ     1024
#define NTOK    (BATCH*SEQ)
#define QKD     (HEAD_D + ROPE_D)   // 96

// ---------------- fp32 tiled GEMM: C[M,N] = A[M,K] @ B[K,N], row-major ----
#define BM 128
#define BN 128
#define BKK 16
#define TM 8
#define TN 8

__global__ __launch_bounds__(256)
void gemm_f32_kernel(const float* __restrict__ A, const float* __restrict__ B,
                     float* __restrict__ C, int M, int N, int K)
{
    __shared__ float As[BKK][BM + 4];   // A tile transposed: As[k][m]
    __shared__ float Bs[BKK][BN];

    const int tid = threadIdx.x;
    const int tx  = tid & 15;        // N direction
    const int ty  = tid >> 4;        // M direction
    const int bm  = blockIdx.y * BM;
    const int bn  = blockIdx.x * BN;

    float acc[TM][TN];
    #pragma unroll
    for (int i = 0; i < TM; ++i)
        #pragma unroll
        for (int j = 0; j < TN; ++j) acc[i][j] = 0.f;

    for (int kt = 0; kt < K; kt += BKK) {
        // A tile: BM x BKK = 2048 floats = 512 float4 (float4 along K)
        #pragma unroll
        for (int it = 0; it < 2; ++it) {
            int i   = tid + it * 256;          // 0..511
            int row = i >> 2;                  // 0..127
            int k4  = (i & 3) << 2;            // 0,4,8,12
            float4 av = *(const float4*)(A + (size_t)(bm + row) * K + kt + k4);
            As[k4 + 0][row] = av.x;
            As[k4 + 1][row] = av.y;
            As[k4 + 2][row] = av.z;
            As[k4 + 3][row] = av.w;
        }
        // B tile: BKK x BN = 512 float4 (float4 along N), guard for N<BN
        #pragma unroll
        for (int it = 0; it < 2; ++it) {
            int i  = tid + it * 256;
            int kr = i >> 5;                   // 0..15
            int n4 = (i & 31) << 2;            // 0..124
            float4 bv = make_float4(0.f, 0.f, 0.f, 0.f);
            if (bn + n4 < N)
                bv = *(const float4*)(B + (size_t)(kt + kr) * N + bn + n4);
            *(float4*)(&Bs[kr][n4]) = bv;
        }
        __syncthreads();

        #pragma unroll
        for (int k = 0; k < BKK; ++k) {
            float4 a0 = *(const float4*)(&As[k][ty * TM + 0]);
            float4 a1 = *(const float4*)(&As[k][ty * TM + 4]);
            float4 b0 = *(const float4*)(&Bs[k][tx * TN + 0]);
            float4 b1 = *(const float4*)(&Bs[k][tx * TN + 4]);
            float af[TM] = {a0.x, a0.y, a0.z, a0.w, a1.x, a1.y, a1.z, a1.w};
            float bf[TN] = {b0.x, b0.y, b0.z, b0.w, b1.x, b1.y, b1.z, b1.w};
            #pragma unroll
            for (int i = 0; i < TM; ++i)
                #pragma unroll
                for (int j = 0; j < TN; ++j)
                    acc[i][j] += af[i] * bf[j];
        }
        __syncthreads();
    }

    #pragma unroll
    for (int i = 0; i < TM; ++i) {
        int row = bm + ty * TM + i;
        #pragma unroll
        for (int j4 = 0; j4 < TN; j4 += 4) {
            int col = bn + tx * TN + j4;
            if (col < N) {
                float4 v = make_float4(acc[i][j4 + 0], acc[i][j4 + 1],
                                       acc[i][j4 + 2], acc[i][j4 + 3]);
                *(float4*)(C + (size_t)row * N + col) = v;
            }
        }
    }
}

// ---------------- fused attention: one block per (b, h, q-tile of 8) -------
// scores kept entirely in LDS (no HBM round-trip), 2-pass softmax.
#define QT 8
#define KT 32

__global__ __launch_bounds__(256)
void mla_attn_kernel(const float* __restrict__ q_c, const float* __restrict__ q_r,
                     const float* __restrict__ k_c, const float* __restrict__ k_r,
                     const float* __restrict__ v_c, float* __restrict__ attn_out)
{
    __shared__ float s_scores[QT][SEQ + 1];    // 32.8 KB, pad -> 2-way max
    __shared__ float s_q[QT][QKD + 4];         // pad 100: distinct banks per qi
    __shared__ float s_kv[KT][QKD + 1];        // pad 97: conflict-free k reads
    __shared__ float s_v[KT][HEAD_D];          // stride 32: lane d -> bank d
    __shared__ float s_rowsum[QT];

    const int tid = threadIdx.x;
    const int bid = blockIdx.x;
    const int qt  = bid & (SEQ / QT - 1);          // 128 q-tiles
    const int h   = (bid >> 7) & (N_HEADS - 1);
    const int b   = bid >> 14;
    const int q0  = qt * QT;

    // Q tile -> LDS (row: [0..31] = q_c, [32..95] = q_r)
    for (int e = tid; e < QT * QKD; e += 256) {
        int qi = e / QKD, d = e % QKD;
        int s  = q0 + qi;
        float v;
        if (d < HEAD_D)
            v = q_c[((size_t)(b * SEQ + s) * N_HEADS + h) * HEAD_D + d];
        else
            v = q_r[((size_t)(b * SEQ + s) * N_HEADS + h) * ROPE_D + (d - HEAD_D)];
        s_q[qi][d] = v;
    }

    const float scale = rsqrtf((float)QKD);
    const int qi = tid >> 5;       // 0..7  (row)
    const int lk = tid & 31;       // 0..31 (k within tile / lane in row group)

    // ---- pass 1: scores = [q_c|q_r] . [k_c|k_r] / sqrt(96) ----
    for (int k0 = 0; k0 < SEQ; k0 += KT) {
        __syncthreads();           // protect s_kv reuse (and s_q on 1st iter)
        for (int e = tid; e < KT * QKD; e += 256) {
            int kk = e / QKD, d = e % QKD;
            int ks = k0 + kk;
            float v;
            if (d < HEAD_D)
                v = k_c[((size_t)(b * SEQ + ks) * N_HEADS + h) * HEAD_D + d];
            else
                v = k_r[(size_t)(b * SEQ + ks) * ROPE_D + (d - HEAD_D)];
            s_kv[kk][d] = v;
        }
        __syncthreads();
        float p0 = 0.f, p1 = 0.f, p2 = 0.f, p3 = 0.f;   // 4-way ILP
        #pragma unroll
        for (int d = 0; d < QKD; d += 4) {
            p0 += s_q[qi][d + 0] * s_kv[lk][d + 0];
            p1 += s_q[qi][d + 1] * s_kv[lk][d + 1];
            p2 += s_q[qi][d + 2] * s_kv[lk][d + 2];
            p3 += s_q[qi][d + 3] * s_kv[lk][d + 3];
        }
        s_scores[qi][k0 + lk] = ((p0 + p1) + (p2 + p3)) * scale;
    }
    __syncthreads();

    // ---- softmax per row: 32 lanes per row, shuffle reduce ----
    {
        float m = -1e30f;
        for (int k = lk; k < SEQ; k += 32)
            m = fmaxf(m, s_scores[qi][k]);
        #pragma unroll
        for (int off = 16; off; off >>= 1)
            m = fmaxf(m, __shfl_xor(m, off, 64));
        float sum = 0.f;
        for (int k = lk; k < SEQ; k += 32) {
            float e = __expf(s_scores[qi][k] - m);
            s_scores[qi][k] = e;
            sum += e;
        }
        #pragma unroll
        for (int off = 16; off; off >>= 1)
            sum += __shfl_xor(sum, off, 64);
        if (lk == 0) s_rowsum[qi] = sum;
    }

    // ---- pass 2: out = P @ V ----
    const int d = tid & 31;        // one output (qi, d) per thread
    float a0 = 0.f, a1 = 0.f, a2 = 0.f, a3 = 0.f;
    for (int k0 = 0; k0 < SEQ; k0 += KT) {
        __syncthreads();           // 1st iter: also fences softmax writes
        for (int e = tid; e < KT * HEAD_D; e += 256) {
            int kk = e >> 5, dd = e & 31;
            s_v[kk][dd] = v_c[((size_t)(b * SEQ + k0 + kk) * N_HEADS + h) * HEAD_D + dd];
        }
        __syncthreads();
        #pragma unroll
        for (int kk = 0; kk < KT; kk += 4) {
            a0 += s_scores[qi][k0 + kk + 0] * s_v[kk + 0][d];
            a1 += s_scores[qi][k0 + kk + 1] * s_v[kk + 1][d];
            a2 += s_scores[qi][k0 + kk + 2] * s_v[kk + 2][d];
            a3 += s_scores[qi][k0 + kk + 3] * s_v[kk + 3][d];
        }
    }
    float o = ((a0 + a1) + (a2 + a3)) / s_rowsum[qi];
    attn_out[((size_t)(b * SEQ + q0 + qi) * N_HEADS + h) * HEAD_D + d] = o;
}

// ---------------------------------------------------------------------------
extern "C" void kernel_launch(void* const* d_in, const int* in_sizes, int n_in,
                              void* d_out, int out_size, void* d_ws, size_t ws_size,
                              hipStream_t stream)
{
    (void)in_sizes; (void)n_in; (void)out_size; (void)ws_size;

    const float* x        = (const float*)d_in[0];
    const float* Wq_down  = (const float*)d_in[1];
    const float* Wq_up    = (const float*)d_in[2];
    const float* Wq_rope  = (const float*)d_in[3];
    const float* Wkv_down = (const float*)d_in[4];
    const float* Wk_up    = (const float*)d_in[5];
    const float* Wv_up    = (const float*)d_in[6];
    const float* Wk_rope  = (const float*)d_in[7];
    const float* Wo       = (const float*)d_in[8];
    float* out = (float*)d_out;

    // workspace layout (fp32), total ~210 MB
    float* ws = (float*)d_ws;
    float* c_q      = ws;  ws += (size_t)NTOK * LATENT;            // 4 MB
    float* c_kv     = ws;  ws += (size_t)NTOK * LATENT;            // 4 MB
    float* q_c      = ws;  ws += (size_t)NTOK * D_MODEL;           // 33.5 MB
    float* q_r      = ws;  ws += (size_t)NTOK * N_HEADS * ROPE_D;  // 67 MB
    float* k_c      = ws;  ws += (size_t)NTOK * D_MODEL;           // 33.5 MB
    float* v_c      = ws;  ws += (size_t)NTOK * D_MODEL;           // 33.5 MB
    float* k_r      = ws;  ws += (size_t)NTOK * ROPE_D;            // 0.5 MB
    float* attn_out = ws;                                          // 33.5 MB

    dim3 blk(256);
    auto launch_gemm = [&](const float* A, const float* Bm, float* C,
                           int M, int N, int K) {
        dim3 grid((N + BN - 1) / BN, (M + BM - 1) / BM);
        hipLaunchKernelGGL(gemm_f32_kernel, grid, blk, 0, stream, A, Bm, C, M, N, K);
    };

    launch_gemm(x,    Wq_down,  c_q,  NTOK, LATENT,          D_MODEL);
    launch_gemm(x,    Wkv_down, c_kv, NTOK, LATENT,          D_MODEL);
    launch_gemm(c_q,  Wq_up,    q_c,  NTOK, N_HEADS*HEAD_D,  LATENT);
    launch_gemm(x,    Wq_rope,  q_r,  NTOK, N_HEADS*ROPE_D,  D_MODEL);
    launch_gemm(c_kv, Wk_up,    k_c,  NTOK, N_HEADS*HEAD_D,  LATENT);
    launch_gemm(c_kv, Wv_up,    v_c,  NTOK, N_HEADS*HEAD_D,  LATENT);
    launch_gemm(x,    Wk_rope,  k_r,  NTOK, ROPE_D,          D_MODEL);

    hipLaunchKernelGGL(mla_attn_kernel,
                       dim3(BATCH * N_HEADS * (SEQ / QT)), blk, 0, stream,
                       q_c, q_r, k_c, k_r, v_c, attn_out);

    launch_gemm(attn_out, Wo, out, NTOK, D_MODEL, D_MODEL);
}

// Round 2
// 839.160 us; speedup vs baseline: 15.3541x; 15.3541x over previous
//
#include <hip/hip_runtime.h>
#include <hip/hip_bf16.h>
#include <math.h>

#define D_MODEL 4096
#define N_HEADS 128
#define LATENT  512
#define ROPE_D  64
#define HEAD_D  32
#define BATCH   2
#define SEQ     1024
#define NTOK    (BATCH*SEQ)

typedef unsigned short u16;
typedef __attribute__((ext_vector_type(8))) short bf16x8;
typedef __attribute__((ext_vector_type(4))) float f32x4;

__device__ __forceinline__ u16 f2bf(float f) {
    union { float f; unsigned u; } v; v.f = f;
    unsigned r = (v.u + 0x7fffu + ((v.u >> 16) & 1u)) >> 16;
    return (u16)r;
}

__device__ __forceinline__ void gl_lds16(const u16* g, u16* l) {
    __builtin_amdgcn_global_load_lds(
        (const __attribute__((address_space(1))) unsigned int*)g,
        (__attribute__((address_space(3))) unsigned int*)l, 16, 0, 0);
}

// ---------------- cast x: fp32 -> bf16, 8 elems/thread, exact grid ---------
__global__ __launch_bounds__(256)
void cast_x_kernel(const float* __restrict__ in, u16* __restrict__ out)
{
    size_t i = ((size_t)blockIdx.x * 256 + threadIdx.x) * 8;
    float4 a = *(const float4*)(in + i);
    float4 b = *(const float4*)(in + i + 4);
    u16 o[8] = {f2bf(a.x), f2bf(a.y), f2bf(a.z), f2bf(a.w),
                f2bf(b.x), f2bf(b.y), f2bf(b.z), f2bf(b.w)};
    *(bf16x8*)(out + i) = *(bf16x8*)o;
}

// ---------- cast+transpose weights: W[K][N] fp32 -> Wt[Nt][K] bf16 ---------
__global__ __launch_bounds__(256)
void castT_kernel(const float* __restrict__ W, u16* __restrict__ Wt,
                  int K, int N, int Nt)
{
    __shared__ float tile[32][33];
    const int tid = threadIdx.x;
    const int j0 = blockIdx.x * 32;   // N dim
    const int i0 = blockIdx.y * 32;   // K dim
    #pragma unroll
    for (int it = 0; it < 4; ++it) {
        int e = tid + it * 256;
        int r = e >> 5, c = e & 31;
        tile[r][c] = (j0 + c < N) ? W[(size_t)(i0 + r) * N + j0 + c] : 0.f;
    }
    __syncthreads();
    #pragma unroll
    for (int it = 0; it < 4; ++it) {
        int e = tid + it * 256;
        int n = e >> 5, k = e & 31;
        Wt[(size_t)(j0 + n) * K + i0 + k] = f2bf(tile[k][n]);
    }
}

// ------- bf16 GEMM, m97 structure: C[M,N] = A[M,K] @ Bt[N,K]^T -------------
// 128x128 tile, BK=64, 4 waves (64x64 each), global_load_lds + XOR swizzle.
template<int OUTF32>
__global__ __launch_bounds__(256)
void gemm_bf16(const u16* __restrict__ A, const u16* __restrict__ Bt,
               void* __restrict__ Cout, int M, int N, int K)
{
    __shared__ __align__(16) u16 As[128 * 64];
    __shared__ __align__(16) u16 Bs[128 * 64];

    const int tid  = threadIdx.x;
    const int lane = tid & 63;
    const int wave = tid >> 6;
    const int wr = wave >> 1, wc = wave & 1;
    const int bm = blockIdx.y * 128, bn = blockIdx.x * 128;
    const int l15 = lane & 15, lg = lane >> 4;

    f32x4 acc[4][4];
    #pragma unroll
    for (int i = 0; i < 4; ++i)
        #pragma unroll
        for (int j = 0; j < 4; ++j) acc[i][j] = (f32x4){0.f, 0.f, 0.f, 0.f};

    for (int kt = 0; kt < K; kt += 64) {
        __syncthreads();
        #pragma unroll
        for (int i = 0; i < 4; ++i) {          // stage A
            int f = i * 256 + tid;
            int row = f >> 3, c = f & 7;
            int sc = c ^ (row & 7);
            gl_lds16(A + (size_t)(bm + row) * K + kt + sc * 8, As + f * 8);
        }
        #pragma unroll
        for (int i = 0; i < 4; ++i) {          // stage B (Bt rows = C cols)
            int f = i * 256 + tid;
            int row = f >> 3, c = f & 7;
            int sc = c ^ (row & 7);
            gl_lds16(Bt + (size_t)(bn + row) * K + kt + sc * 8, Bs + f * 8);
        }
        __syncthreads();

        #pragma unroll
        for (int t = 0; t < 2; ++t) {
            bf16x8 af[4], bf[4];
            #pragma unroll
            for (int fm = 0; fm < 4; ++fm) {
                int row = wr * 64 + fm * 16 + l15;
                int c = (t * 4 + lg) ^ (row & 7);
                af[fm] = *(const bf16x8*)(As + row * 64 + c * 8);
            }
            #pragma unroll
            for (int fn = 0; fn < 4; ++fn) {
                int row = wc * 64 + fn * 16 + l15;
                int c = (t * 4 + lg) ^ (row & 7);
                bf[fn] = *(const bf16x8*)(Bs + row * 64 + c * 8);
            }
            #pragma unroll
            for (int fm = 0; fm < 4; ++fm)
                #pragma unroll
                for (int fn = 0; fn < 4; ++fn)
                    acc[fm][fn] = __builtin_amdgcn_mfma_f32_16x16x32_bf16(
                        af[fm], bf[fn], acc[fm][fn], 0, 0, 0);
        }
    }

    #pragma unroll
    for (int fm = 0; fm < 4; ++fm)
        #pragma unroll
        for (int fn = 0; fn < 4; ++fn)
            #pragma unroll
            for (int ri = 0; ri < 4; ++ri) {
                int row = bm + wr * 64 + fm * 16 + 4 * lg + ri;
                int col = bn + wc * 64 + fn * 16 + l15;
                if (col < N) {
                    float v = acc[fm][fn][ri];
                    if (OUTF32) ((float*)Cout)[(size_t)row * N + col] = v;
                    else        ((u16*)Cout)[(size_t)row * N + col] = f2bf(v);
                }
            }
}

// ---------- transpose v_c[b*S+s][4096] -> vt[(b*4096+col)][1024] -----------
__global__ __launch_bounds__(256)
void vtrans_kernel(const u16* __restrict__ vc, u16* __restrict__ vt)
{
    __shared__ __align__(16) u16 tile[64][72];
    const int tid = threadIdx.x;
    const int c0 = blockIdx.x * 64;     // col (dim) tile
    const int s0 = blockIdx.y * 64;     // seq tile
    const int b  = blockIdx.z;
    #pragma unroll
    for (int it = 0; it < 2; ++it) {
        int e = it * 256 + tid;
        int r = e >> 3, c8 = e & 7;
        *(bf16x8*)&tile[r][c8 * 8] =
            *(const bf16x8*)(vc + (size_t)(b * SEQ + s0 + r) * D_MODEL + c0 + c8 * 8);
    }
    __syncthreads();
    #pragma unroll
    for (int it = 0; it < 2; ++it) {
        int e = it * 256 + tid;
        int d = e >> 3, c8 = e & 7;     // output row = dim, chunk along s
        u16 o[8];
        #pragma unroll
        for (int j = 0; j < 8; ++j) o[j] = tile[c8 * 8 + j][d];
        *(bf16x8*)(vt + (size_t)(b * D_MODEL + c0 + d) * SEQ + s0 + c8 * 8) = *(bf16x8*)o;
    }
}

// ---------------- MFMA flash attention ------------------------------------
// block = (q-tile of 64, head, batch); 4 waves x 16 q-rows; K-tiles of 64.
__global__ __launch_bounds__(256)
void attn_kernel(const u16* __restrict__ q_c, const u16* __restrict__ q_r,
                 const u16* __restrict__ k_c, const u16* __restrict__ k_r,
                 const u16* __restrict__ vt,  u16* __restrict__ attn_out)
{
    __shared__ __align__(16) u16 s_k[64][104];   // dims 0-31 = k_c, 32-95 = k_r
    __shared__ __align__(16) u16 s_vt[32][72];   // [dim][token]
    __shared__ __align__(16) u16 s_p[4][16][72]; // per-wave P [qrow][kpos]

    const int tid  = threadIdx.x;
    const int lane = tid & 63;
    const int w    = tid >> 6;
    const int l15 = lane & 15, lg = lane >> 4;
    const int q0 = blockIdx.x * 64;
    const int h  = blockIdx.y;
    const int b  = blockIdx.z;
    const float scale = 0.1020620726159658f;   // 1/sqrt(96)

    // Q fragments in registers (A-operand): rows = q0+w*16+l15
    const int qrow = q0 + w * 16 + l15;
    bf16x8 qf[3];
    qf[0] = *(const bf16x8*)(q_c + (size_t)(b * SEQ + qrow) * D_MODEL + h * HEAD_D + lg * 8);
    qf[1] = *(const bf16x8*)(q_r + (size_t)(b * SEQ + qrow) * (N_HEADS * ROPE_D) + h * ROPE_D + lg * 8);
    qf[2] = *(const bf16x8*)(q_r + (size_t)(b * SEQ + qrow) * (N_HEADS * ROPE_D) + h * ROPE_D + 32 + lg * 8);

    float m[4] = {-1e30f, -1e30f, -1e30f, -1e30f};
    float lsum[4] = {0.f, 0.f, 0.f, 0.f};
    f32x4 oacc[2];
    oacc[0] = (f32x4){0.f, 0.f, 0.f, 0.f};
    oacc[1] = (f32x4){0.f, 0.f, 0.f, 0.f};

    for (int k0 = 0; k0 < SEQ; k0 += 64) {
        __syncthreads();
        { // stage K tile: k_c part (1 chunk/thread)
            int row = tid >> 2, c = tid & 3;
            *(bf16x8*)&s_k[row][c * 8] =
                *(const bf16x8*)(k_c + (size_t)(b * SEQ + k0 + row) * D_MODEL + h * HEAD_D + c * 8);
        }
        #pragma unroll
        for (int it = 0; it < 2; ++it) { // k_r part (2 chunks/thread)
            int i = it * 256 + tid;
            int row = i >> 3, c = i & 7;
            *(bf16x8*)&s_k[row][32 + c * 8] =
                *(const bf16x8*)(k_r + (size_t)(b * SEQ + k0 + row) * ROPE_D + c * 8);
        }
        { // stage V^T tile (1 chunk/thread)
            int d = tid >> 3, c = tid & 7;
            *(bf16x8*)&s_vt[d][c * 8] =
                *(const bf16x8*)(vt + (size_t)(b * D_MODEL + h * HEAD_D + d) * SEQ + k0 + c * 8);
        }
        __syncthreads();

        // ---- QK^T: S[16q][64k] ----
        f32x4 sc[4];
        #pragma unroll
        for (int fc = 0; fc < 4; ++fc) sc[fc] = (f32x4){0.f, 0.f, 0.f, 0.f};
        #pragma unroll
        for (int t = 0; t < 3; ++t) {
            bf16x8 kb[4];
            #pragma unroll
            for (int fc = 0; fc < 4; ++fc)
                kb[fc] = *(const bf16x8*)&s_k[fc * 16 + l15][t * 32 + lg * 8];
            #pragma unroll
            for (int fc = 0; fc < 4; ++fc)
                sc[fc] = __builtin_amdgcn_mfma_f32_16x16x32_bf16(qf[t], kb[fc], sc[fc], 0, 0, 0);
        }

        // ---- online softmax update ----
        float tm[4], corr[4], rs[4];
        #pragma unroll
        for (int ri = 0; ri < 4; ++ri) {
            tm[ri] = fmaxf(fmaxf(sc[0][ri], sc[1][ri]), fmaxf(sc[2][ri], sc[3][ri])) * scale;
            #pragma unroll
            for (int off = 1; off <= 8; off <<= 1)
                tm[ri] = fmaxf(tm[ri], __shfl_xor(tm[ri], off));
            float mn = fmaxf(m[ri], tm[ri]);
            corr[ri] = __expf(m[ri] - mn);
            m[ri] = mn;
            rs[ri] = 0.f;
        }
        #pragma unroll
        for (int fc = 0; fc < 4; ++fc)
            #pragma unroll
            for (int ri = 0; ri < 4; ++ri) {
                float p = __expf(sc[fc][ri] * scale - m[ri]);
                rs[ri] += p;
                s_p[w][4 * lg + ri][fc * 16 + l15] = f2bf(p);
            }
        #pragma unroll
        for (int ri = 0; ri < 4; ++ri) {
            #pragma unroll
            for (int off = 1; off <= 8; off <<= 1)
                rs[ri] += __shfl_xor(rs[ri], off);
            lsum[ri] = lsum[ri] * corr[ri] + rs[ri];
        }
        #pragma unroll
        for (int fd = 0; fd < 2; ++fd)
            #pragma unroll
            for (int ri = 0; ri < 4; ++ri)
                oacc[fd][ri] *= corr[ri];

        // ---- PV: O[16q][32d] += P[16][64] @ V[64][32] ----
        #pragma unroll
        for (int t2 = 0; t2 < 2; ++t2) {
            bf16x8 pa = *(const bf16x8*)&s_p[w][l15][t2 * 32 + lg * 8];
            #pragma unroll
            for (int fd = 0; fd < 2; ++fd) {
                bf16x8 vb = *(const bf16x8*)&s_vt[fd * 16 + l15][t2 * 32 + lg * 8];
                oacc[fd] = __builtin_amdgcn_mfma_f32_16x16x32_bf16(pa, vb, oacc[fd], 0, 0, 0);
            }
        }
    }

    #pragma unroll
    for (int fd = 0; fd < 2; ++fd)
        #pragma unroll
        for (int ri = 0; ri < 4; ++ri) {
            int row = q0 + w * 16 + 4 * lg + ri;
            attn_out[(size_t)(b * SEQ + row) * D_MODEL + h * HEAD_D + fd * 16 + l15] =
                f2bf(oacc[fd][ri] / lsum[ri]);
        }
}

// ---------------------------------------------------------------------------
extern "C" void kernel_launch(void* const* d_in, const int* in_sizes, int n_in,
                              void* d_out, int out_size, void* d_ws, size_t ws_size,
                              hipStream_t stream)
{
    (void)in_sizes; (void)n_in; (void)out_size; (void)ws_size;

    const float* x        = (const float*)d_in[0];
    const float* Wq_down  = (const float*)d_in[1];
    const float* Wq_up    = (const float*)d_in[2];
    const float* Wq_rope  = (const float*)d_in[3];
    const float* Wkv_down = (const float*)d_in[4];
    const float* Wk_up    = (const float*)d_in[5];
    const float* Wv_up    = (const float*)d_in[6];
    const float* Wk_rope  = (const float*)d_in[7];
    const float* Wo       = (const float*)d_in[8];

    u16* p = (u16*)d_ws;
    u16* xb   = p; p += (size_t)NTOK * D_MODEL;          // also attn_out later
    u16* big  = p; p += (size_t)8192 * 4096;             // WrqT, then WoT+vt
    u16* WdqT = p; p += (size_t)512 * 4096;
    u16* WuqT = p; p += (size_t)4096 * 512;
    u16* WdkvT= p; p += (size_t)512 * 4096;
    u16* WukT = p; p += (size_t)4096 * 512;
    u16* WuvT = p; p += (size_t)4096 * 512;
    u16* WrkT = p; p += (size_t)128 * 4096;
    u16* c_q  = p; p += (size_t)NTOK * LATENT;
    u16* c_kv = p; p += (size_t)NTOK * LATENT;
    u16* q_c  = p; p += (size_t)NTOK * D_MODEL;
    u16* q_r  = p; p += (size_t)NTOK * N_HEADS * ROPE_D;
    u16* k_c  = p; p += (size_t)NTOK * D_MODEL;
    u16* v_c  = p; p += (size_t)NTOK * D_MODEL;
    u16* k_r  = p; p += (size_t)NTOK * ROPE_D;
    u16* WoT  = big;                                     // after q_r GEMM
    u16* vt   = big + (size_t)4096 * 4096;
    u16* attn_out = xb;                                  // after last xb use

    dim3 blk(256);

    // 1. cast x
    hipLaunchKernelGGL(cast_x_kernel, dim3((NTOK * D_MODEL) / (256 * 8)), blk, 0, stream, x, xb);
    // 2. Wq_rope^T, then the big q_r GEMM (frees `big` for WoT+vt)
    hipLaunchKernelGGL(castT_kernel, dim3(8192 / 32, 4096 / 32), blk, 0, stream, Wq_rope, big, 4096, 8192, 8192);
    gemm_bf16<0><<<dim3(8192 / 128, NTOK / 128), blk, 0, stream>>>(xb, big, q_r, NTOK, 8192, 4096);
    // 3. remaining weight transposes
    hipLaunchKernelGGL(castT_kernel, dim3(512 / 32, 4096 / 32), blk, 0, stream, Wq_down, WdqT, 4096, 512, 512);
    hipLaunchKernelGGL(castT_kernel, dim3(4096 / 32, 512 / 32), blk, 0, stream, Wq_up, WuqT, 512, 4096, 4096);
    hipLaunchKernelGGL(castT_kernel, dim3(512 / 32, 4096 / 32), blk, 0, stream, Wkv_down, WdkvT, 4096, 512, 512);
    hipLaunchKernelGGL(castT_kernel, dim3(4096 / 32, 512 / 32), blk, 0, stream, Wk_up, WukT, 512, 4096, 4096);
    hipLaunchKernelGGL(castT_kernel, dim3(4096 / 32, 512 / 32), blk, 0, stream, Wv_up, WuvT, 512, 4096, 4096);
    hipLaunchKernelGGL(castT_kernel, dim3(128 / 32, 4096 / 32), blk, 0, stream, Wk_rope, WrkT, 4096, 64, 128);
    hipLaunchKernelGGL(castT_kernel, dim3(4096 / 32, 4096 / 32), blk, 0, stream, Wo, WoT, 4096, 4096, 4096);
    // 4. projection GEMMs
    gemm_bf16<0><<<dim3(512 / 128, NTOK / 128), blk, 0, stream>>>(xb, WdqT, c_q, NTOK, 512, 4096);
    gemm_bf16<0><<<dim3(512 / 128, NTOK / 128), blk, 0, stream>>>(xb, WdkvT, c_kv, NTOK, 512, 4096);
    gemm_bf16<0><<<dim3(4096 / 128, NTOK / 128), blk, 0, stream>>>(c_q, WuqT, q_c, NTOK, 4096, 512);
    gemm_bf16<0><<<dim3(4096 / 128, NTOK / 128), blk, 0, stream>>>(c_kv, WukT, k_c, NTOK, 4096, 512);
    gemm_bf16<0><<<dim3(4096 / 128, NTOK / 128), blk, 0, stream>>>(c_kv, WuvT, v_c, NTOK, 4096, 512);
    gemm_bf16<0><<<dim3(1, NTOK / 128), blk, 0, stream>>>(xb, WrkT, k_r, NTOK, 64, 4096);
    // 5. V transpose, attention
    hipLaunchKernelGGL(vtrans_kernel, dim3(4096 / 64, SEQ / 64, BATCH), blk, 0, stream, v_c, vt);
    hipLaunchKernelGGL(attn_kernel, dim3(SEQ / 64, N_HEADS, BATCH), blk, 0, stream,
                       q_c, q_r, k_c, k_r, vt, attn_out);
    // 6. output projection (fp32 out)
    gemm_bf16<1><<<dim3(4096 / 128, NTOK / 128), blk, 0, stream>>>(attn_out, WoT, d_out, NTOK, 4096, 4096);
}

// Round 3
// 594.779 us; speedup vs baseline: 21.6627x; 1.4109x over previous
//
#include <hip/hip_runtime.h>
#include <hip/hip_bf16.h>
#include <math.h>

#define D_MODEL 4096
#define N_HEADS 128
#define LATENT  512
#define ROPE_D  64
#define HEAD_D  32
#define BATCH   2
#define SEQ     1024
#define NTOK    (BATCH*SEQ)

typedef unsigned short u16;
typedef __attribute__((ext_vector_type(8))) short bf16x8;
typedef __attribute__((ext_vector_type(4))) float f32x4;

__device__ __forceinline__ u16 f2bf(float f) {
    union { float f; unsigned u; } v; v.f = f;
    unsigned r = (v.u + 0x7fffu + ((v.u >> 16) & 1u)) >> 16;
    return (u16)r;
}

__device__ __forceinline__ void gl_lds16(const u16* g, u16* l) {
    __builtin_amdgcn_global_load_lds(
        (const __attribute__((address_space(1))) unsigned int*)g,
        (__attribute__((address_space(3))) unsigned int*)l, 16, 0, 0);
}

// ---------------- cast x: fp32 -> bf16 -------------------------------------
__global__ __launch_bounds__(256)
void cast_x_kernel(const float* __restrict__ in, u16* __restrict__ out)
{
    size_t i = ((size_t)blockIdx.x * 256 + threadIdx.x) * 8;
    float4 a = *(const float4*)(in + i);
    float4 b = *(const float4*)(in + i + 4);
    u16 o[8] = {f2bf(a.x), f2bf(a.y), f2bf(a.z), f2bf(a.w),
                f2bf(b.x), f2bf(b.y), f2bf(b.z), f2bf(b.w)};
    *(bf16x8*)(out + i) = *(bf16x8*)o;
}

// ---------- cast+transpose weights: W[K][N] fp32 -> Wt[N][K] bf16 ----------
__global__ __launch_bounds__(256)
void castT_kernel(const float* __restrict__ W, u16* __restrict__ Wt,
                  int K, int N)
{
    __shared__ float tile[32][33];
    const int tid = threadIdx.x;
    const int j0 = blockIdx.x * 32;   // N dim
    const int i0 = blockIdx.y * 32;   // K dim
    #pragma unroll
    for (int it = 0; it < 4; ++it) {
        int e = tid + it * 256;
        int r = e >> 5, c = e & 31;
        tile[r][c] = (j0 + c < N) ? W[(size_t)(i0 + r) * N + j0 + c] : 0.f;
    }
    __syncthreads();
    #pragma unroll
    for (int it = 0; it < 4; ++it) {
        int e = tid + it * 256;
        int n = e >> 5, k = e & 31;
        Wt[(size_t)(j0 + n) * K + i0 + k] = f2bf(tile[k][n]);
    }
}

// ------- bf16 GEMM, m97 structure + strides + XCD swizzle ------------------
template<int OUTF32>
__global__ __launch_bounds__(256)
void gemm_bf16(const u16* __restrict__ A, const u16* __restrict__ Bt,
               void* __restrict__ Cout, int M, int N, int K,
               int lda, int ldb, int ldc)
{
    __shared__ __align__(16) u16 As[128 * 64];
    __shared__ __align__(16) u16 Bs[128 * 64];

    const int tid  = threadIdx.x;
    const int lane = tid & 63;
    const int wave = tid >> 6;
    const int wr = wave >> 1, wc = wave & 1;
    // XCD-aware swizzle (all grids used have nwg % 8 == 0)
    const int nwg  = gridDim.x * gridDim.y;
    const int orig = blockIdx.y * gridDim.x + blockIdx.x;
    const int swz  = (orig & 7) * (nwg >> 3) + (orig >> 3);
    const int bm = (swz / gridDim.x) * 128, bn = (swz % gridDim.x) * 128;
    const int l15 = lane & 15, lg = lane >> 4;

    f32x4 acc[4][4];
    #pragma unroll
    for (int i = 0; i < 4; ++i)
        #pragma unroll
        for (int j = 0; j < 4; ++j) acc[i][j] = (f32x4){0.f, 0.f, 0.f, 0.f};

    for (int kt = 0; kt < K; kt += 64) {
        __syncthreads();
        #pragma unroll
        for (int i = 0; i < 4; ++i) {          // stage A
            int f = i * 256 + tid;
            int row = f >> 3, c = f & 7;
            int sc = c ^ (row & 7);
            gl_lds16(A + (size_t)(bm + row) * lda + kt + sc * 8, As + f * 8);
        }
        #pragma unroll
        for (int i = 0; i < 4; ++i) {          // stage B
            int f = i * 256 + tid;
            int row = f >> 3, c = f & 7;
            int sc = c ^ (row & 7);
            gl_lds16(Bt + (size_t)(bn + row) * ldb + kt + sc * 8, Bs + f * 8);
        }
        __syncthreads();

        #pragma unroll
        for (int t = 0; t < 2; ++t) {
            bf16x8 af[4], bf[4];
            #pragma unroll
            for (int fm = 0; fm < 4; ++fm) {
                int row = wr * 64 + fm * 16 + l15;
                int c = (t * 4 + lg) ^ (row & 7);
                af[fm] = *(const bf16x8*)(As + row * 64 + c * 8);
            }
            #pragma unroll
            for (int fn = 0; fn < 4; ++fn) {
                int row = wc * 64 + fn * 16 + l15;
                int c = (t * 4 + lg) ^ (row & 7);
                bf[fn] = *(const bf16x8*)(Bs + row * 64 + c * 8);
            }
            #pragma unroll
            for (int fm = 0; fm < 4; ++fm)
                #pragma unroll
                for (int fn = 0; fn < 4; ++fn)
                    acc[fm][fn] = __builtin_amdgcn_mfma_f32_16x16x32_bf16(
                        af[fm], bf[fn], acc[fm][fn], 0, 0, 0);
        }
    }

    #pragma unroll
    for (int fm = 0; fm < 4; ++fm)
        #pragma unroll
        for (int fn = 0; fn < 4; ++fn)
            #pragma unroll
            for (int ri = 0; ri < 4; ++ri) {
                int row = bm + wr * 64 + fm * 16 + 4 * lg + ri;
                int col = bn + wc * 64 + fn * 16 + l15;
                if (col < N) {
                    float v = acc[fm][fn][ri];
                    if (OUTF32) ((float*)Cout)[(size_t)row * ldc + col] = v;
                    else        ((u16*)Cout)[(size_t)row * ldc + col] = f2bf(v);
                }
            }
}

// ---------- transpose v_c (in C2, stride 8192, col base 4096) -> vt --------
__global__ __launch_bounds__(256)
void vtrans_kernel(const u16* __restrict__ vc, u16* __restrict__ vt)
{
    __shared__ __align__(16) u16 tile[64][72];
    const int tid = threadIdx.x;
    const int c0 = blockIdx.x * 64;     // dim tile (0..4095)
    const int s0 = blockIdx.y * 64;     // seq tile
    const int b  = blockIdx.z;
    #pragma unroll
    for (int it = 0; it < 2; ++it) {
        int e = it * 256 + tid;
        int r = e >> 3, c8 = e & 7;
        *(bf16x8*)&tile[r][c8 * 8] =
            *(const bf16x8*)(vc + (size_t)(b * SEQ + s0 + r) * 8192 + c0 + c8 * 8);
    }
    __syncthreads();
    #pragma unroll
    for (int it = 0; it < 2; ++it) {
        int e = it * 256 + tid;
        int d = e >> 3, c8 = e & 7;
        u16 o[8];
        #pragma unroll
        for (int j = 0; j < 8; ++j) o[j] = tile[c8 * 8 + j][d];
        *(bf16x8*)(vt + (size_t)(b * D_MODEL + c0 + d) * SEQ + s0 + c8 * 8) = *(bf16x8*)o;
    }
}

// ---------------- MFMA flash attention (swapped QK, swizzled LDS) ----------
// block = (64 q-rows, head, batch); 4 waves x 16 q; K-tiles of 64, 2-ph dbuf.
__global__ __launch_bounds__(256)
void attn_kernel(const u16* __restrict__ q_c, const u16* __restrict__ q_r,
                 const u16* __restrict__ k_c, const u16* __restrict__ k_r,
                 const u16* __restrict__ vt,  u16* __restrict__ attn_out)
{
    __shared__ __align__(16) u16 s_kc[2][64 * 32];
    __shared__ __align__(16) u16 s_kr[2][64 * 64];
    __shared__ __align__(16) u16 s_vt[2][32 * 64];
    __shared__ __align__(16) u16 s_p[4][16 * 64];

    const int tid  = threadIdx.x;
    const int lane = tid & 63;
    const int w    = tid >> 6;
    const int l15  = lane & 15, lg = lane >> 4;
    const int q0 = blockIdx.x * 64;
    const int h  = blockIdx.y;
    const int b  = blockIdx.z;
    const size_t bS = (size_t)b * SEQ;
    const int hc = h * HEAD_D;
    const float c2 = 0.1020620726159658f * 1.44269504088896f; // log2e/sqrt(96)

    // Q fragments (B-operand: col = l15 = q-row, contraction chunk = lg*8)
    const int qrow = q0 + w * 16 + l15;
    const bf16x8 qf0 = *(const bf16x8*)(q_c + (bS + qrow) * 4096 + hc + lg * 8);
    const bf16x8 qf1 = *(const bf16x8*)(q_r + (bS + qrow) * 9344 + h * ROPE_D + lg * 8);
    const bf16x8 qf2 = *(const bf16x8*)(q_r + (bS + qrow) * 9344 + h * ROPE_D + 32 + lg * 8);

    float m2 = -1e30f, lsum = 0.f;     // log2-domain running max / denom
    f32x4 oacc[2];
    oacc[0] = (f32x4){0.f, 0.f, 0.f, 0.f};
    oacc[1] = (f32x4){0.f, 0.f, 0.f, 0.f};

    auto stage = [&](int buf, int k0) {
        { int f = tid, r = f >> 2, c = f & 3;     // k_c: 64x32, 4 chunks/row
          gl_lds16(k_c + (bS + k0 + r) * 8192 + hc + ((c ^ (r & 3)) << 3),
                   &s_kc[buf][f * 8]); }
        #pragma unroll
        for (int it = 0; it < 2; ++it) {          // k_r: 64x64, 8 chunks/row
          int f = it * 256 + tid, r = f >> 3, c = f & 7;
          gl_lds16(k_r + (bS + k0 + r) * 9344 + ((c ^ (r & 7)) << 3),
                   &s_kr[buf][f * 8]); }
        { int f = tid, d = f >> 3, c = f & 7;     // v^T: 32x64
          gl_lds16(vt + ((size_t)b * D_MODEL + hc + d) * SEQ + k0 + ((c ^ (d & 7)) << 3),
                   &s_vt[buf][f * 8]); }
    };

    stage(0, 0);
    __syncthreads();

    int cur = 0;
    for (int t = 0; t < SEQ / 64; ++t) {
        if (t + 1 < SEQ / 64) stage(cur ^ 1, (t + 1) * 64);

        // ---- QK^T swapped: sc[fc] = P^T tile (rows=k, cols=q) ----
        f32x4 sc[4];
        #pragma unroll
        for (int fc = 0; fc < 4; ++fc) sc[fc] = (f32x4){0.f, 0.f, 0.f, 0.f};
        __builtin_amdgcn_s_setprio(1);
        #pragma unroll
        for (int fc = 0; fc < 4; ++fc) {
            int row = fc * 16 + l15;
            bf16x8 kb = *(const bf16x8*)&s_kc[cur][row * 32 + ((lg ^ (row & 3)) << 3)];
            sc[fc] = __builtin_amdgcn_mfma_f32_16x16x32_bf16(kb, qf0, sc[fc], 0, 0, 0);
        }
        #pragma unroll
        for (int tt = 0; tt < 2; ++tt) {
            bf16x8 qf = tt ? qf2 : qf1;
            #pragma unroll
            for (int fc = 0; fc < 4; ++fc) {
                int row = fc * 16 + l15;
                bf16x8 kb = *(const bf16x8*)&s_kr[cur][row * 64 + (((tt * 4 + lg) ^ (row & 7)) << 3)];
                sc[fc] = __builtin_amdgcn_mfma_f32_16x16x32_bf16(kb, qf, sc[fc], 0, 0, 0);
            }
        }
        __builtin_amdgcn_s_setprio(0);

        // ---- softmax: lane owns q=l15; 16 values; reduce over lg ----
        float tmx = sc[0][0];
        #pragma unroll
        for (int fc = 0; fc < 4; ++fc)
            #pragma unroll
            for (int ri = 0; ri < 4; ++ri)
                tmx = fmaxf(tmx, sc[fc][ri]);
        tmx = fmaxf(tmx, __shfl_xor(tmx, 16));
        tmx = fmaxf(tmx, __shfl_xor(tmx, 32));
        float tl2 = tmx * c2;
        if (!__all(tl2 <= m2 + 8.f)) {        // T13 defer-max rescale
            float mn = fmaxf(m2, tl2);
            float corr = exp2f(m2 - mn);
            m2 = mn;
            lsum *= corr;
            #pragma unroll
            for (int ri = 0; ri < 4; ++ri) {
                float cr = __shfl(corr, 4 * lg + ri);
                oacc[0][ri] *= cr; oacc[1][ri] *= cr;
            }
        }
        float rs = 0.f;
        unsigned pk0[4], pk1[4];
        #pragma unroll
        for (int fc = 0; fc < 4; ++fc) {
            float p0 = exp2f(fmaf(sc[fc][0], c2, -m2));
            float p1 = exp2f(fmaf(sc[fc][1], c2, -m2));
            float p2 = exp2f(fmaf(sc[fc][2], c2, -m2));
            float p3 = exp2f(fmaf(sc[fc][3], c2, -m2));
            rs += (p0 + p1) + (p2 + p3);
            asm("v_cvt_pk_bf16_f32 %0, %1, %2" : "=v"(pk0[fc]) : "v"(p0), "v"(p1));
            asm("v_cvt_pk_bf16_f32 %0, %1, %2" : "=v"(pk1[fc]) : "v"(p2), "v"(p3));
        }
        rs += __shfl_xor(rs, 16);
        rs += __shfl_xor(rs, 32);
        lsum += rs;
        // write P quads: row l15, data chunk 2fc+(lg>>1), half lg&1, XOR-swz
        #pragma unroll
        for (int fc = 0; fc < 4; ++fc) {
            int ch = (2 * fc + (lg >> 1)) ^ (l15 & 7);
            *(uint2*)&s_p[w][l15 * 64 + ch * 8 + 4 * (lg & 1)] =
                make_uint2(pk0[fc], pk1[fc]);
        }

        // ---- PV ----
        __builtin_amdgcn_s_setprio(1);
        #pragma unroll
        for (int t2 = 0; t2 < 2; ++t2) {
            bf16x8 pa = *(const bf16x8*)&s_p[w][l15 * 64 + (((t2 * 4 + lg) ^ (l15 & 7)) << 3)];
            #pragma unroll
            for (int fd = 0; fd < 2; ++fd) {
                int row = fd * 16 + l15;
                bf16x8 vb = *(const bf16x8*)&s_vt[cur][row * 64 + (((t2 * 4 + lg) ^ (row & 7)) << 3)];
                oacc[fd] = __builtin_amdgcn_mfma_f32_16x16x32_bf16(pa, vb, oacc[fd], 0, 0, 0);
            }
        }
        __builtin_amdgcn_s_setprio(0);

        __syncthreads();
        cur ^= 1;
    }

    #pragma unroll
    for (int ri = 0; ri < 4; ++ri) {
        float ls = __shfl(lsum, 4 * lg + ri);
        float inv = 1.f / ls;
        int row = q0 + w * 16 + 4 * lg + ri;
        attn_out[(bS + row) * 4096 + hc + l15]      = f2bf(oacc[0][ri] * inv);
        attn_out[(bS + row) * 4096 + hc + 16 + l15] = f2bf(oacc[1][ri] * inv);
    }
}

// ---------------------------------------------------------------------------
extern "C" void kernel_launch(void* const* d_in, const int* in_sizes, int n_in,
                              void* d_out, int out_size, void* d_ws, size_t ws_size,
                              hipStream_t stream)
{
    (void)in_sizes; (void)n_in; (void)out_size; (void)ws_size;

    const float* x        = (const float*)d_in[0];
    const float* Wq_down  = (const float*)d_in[1];
    const float* Wq_up    = (const float*)d_in[2];
    const float* Wq_rope  = (const float*)d_in[3];
    const float* Wkv_down = (const float*)d_in[4];
    const float* Wk_up    = (const float*)d_in[5];
    const float* Wv_up    = (const float*)d_in[6];
    const float* Wk_rope  = (const float*)d_in[7];
    const float* Wo       = (const float*)d_in[8];

    // workspace (u16 units), ~178 MB total
    u16* ws   = (u16*)d_ws;
    u16* xb   = ws;                                  //  8,388,608  (x bf16; later attn_out)
    u16* BigT = xb + (size_t)8388608;                // 38,273,024  (9344 x 4096)
    u16* UpT  = BigT + (size_t)38273024;             //  4,194,304  (8192 x 512: Wk_up|Wv_up ^T)
    u16* WuqT = UpT + (size_t)4194304;               //  2,097,152  (4096 x 512)
    u16* C_big= WuqT + (size_t)2097152;              // 19,136,512  (2048 x 9344)
    u16* C2   = C_big + (size_t)19136512;            // 16,777,216  (2048 x 8192: k_c|v_c)
    // BigT reused after GEMM1:
    u16* WoT  = BigT;                                //  4096 x 4096
    u16* vt   = BigT + (size_t)16777216;             //  2 x 4096 x 1024
    u16* q_c  = BigT + (size_t)25165824;             //  2048 x 4096
    u16* attn_out = xb;

    dim3 blk(256);

    // zero the 64 pad rows of BigT (rows 9280..9343)
    hipMemsetAsync(BigT + (size_t)9280 * 4096, 0, (size_t)64 * 4096 * 2, stream);
    // cast x -> bf16
    hipLaunchKernelGGL(cast_x_kernel, dim3(4096), blk, 0, stream, x, xb);
    // weight transposes into BigT: rows [0,8192)=Wq_rope^T, [8192,8704)=Wq_down^T,
    // [8704,9216)=Wkv_down^T, [9216,9280)=Wk_rope^T
    hipLaunchKernelGGL(castT_kernel, dim3(256, 128), blk, 0, stream, Wq_rope, BigT, 4096, 8192);
    hipLaunchKernelGGL(castT_kernel, dim3(16, 128), blk, 0, stream, Wq_down, BigT + (size_t)8192 * 4096, 4096, 512);
    hipLaunchKernelGGL(castT_kernel, dim3(16, 128), blk, 0, stream, Wkv_down, BigT + (size_t)8704 * 4096, 4096, 512);
    hipLaunchKernelGGL(castT_kernel, dim3(2, 128), blk, 0, stream, Wk_rope, BigT + (size_t)9216 * 4096, 4096, 64);
    hipLaunchKernelGGL(castT_kernel, dim3(128, 16), blk, 0, stream, Wk_up, UpT, 512, 4096);
    hipLaunchKernelGGL(castT_kernel, dim3(128, 16), blk, 0, stream, Wv_up, UpT + (size_t)4096 * 512, 512, 4096);
    hipLaunchKernelGGL(castT_kernel, dim3(128, 16), blk, 0, stream, Wq_up, WuqT, 512, 4096);

    // GEMM1 (merged down/rope projections): C_big = xb @ BigT^T
    gemm_bf16<0><<<dim3(73, 16), blk, 0, stream>>>(xb, BigT, C_big, NTOK, 9344, 4096, 4096, 4096, 9344);
    // Wo^T into freed BigT
    hipLaunchKernelGGL(castT_kernel, dim3(128, 128), blk, 0, stream, Wo, WoT, 4096, 4096);
    // GEMM2: k_c|v_c = c_kv @ [Wk_up|Wv_up]^T
    gemm_bf16<0><<<dim3(64, 16), blk, 0, stream>>>(C_big + 8704, UpT, C2, NTOK, 8192, 512, 9344, 512, 8192);
    // GEMM3: q_c = c_q @ Wq_up^T
    gemm_bf16<0><<<dim3(32, 16), blk, 0, stream>>>(C_big + 8192, WuqT, q_c, NTOK, 4096, 512, 9344, 512, 4096);
    // V transpose, attention
    hipLaunchKernelGGL(vtrans_kernel, dim3(64, 16, 2), blk, 0, stream, C2 + 4096, vt);
    hipLaunchKernelGGL(attn_kernel, dim3(16, 128, 2), blk, 0, stream,
                       q_c, C_big, C2, C_big + 9216, vt, attn_out);
    // output projection (fp32 out)
    gemm_bf16<1><<<dim3(32, 16), blk, 0, stream>>>(attn_out, WoT, d_out, NTOK, 4096, 4096, 4096, 4096, 4096);
}